// Round 4
// baseline (1025.895 us; speedup 1.0000x reference)
//
#include <hip/hip_runtime.h>
#include <hip/hip_bf16.h>
#include <stdint.h>

typedef __bf16 bf16_t;
typedef __bf16 bf16x8 __attribute__((ext_vector_type(8)));
typedef _Float16 f16;
typedef _Float16 f16x8 __attribute__((ext_vector_type(8)));
typedef _Float16 h2 __attribute__((ext_vector_type(2)));
typedef float floatx4 __attribute__((ext_vector_type(4)));
typedef uint32_t u32;

#define M_DIM 4096
#define K_DIM 4096
#define N_DIM 11008
#define GRP 128
#define NHALF (N_DIM / 2)        // 5504
#define N64T (N_DIM / 64)        // 172
#define KTN (K_DIM / 64)         // 64
#define WB_DWORDS (N64T * KTN * 64 * 8)  // 5,636,096 dwords
#define WB_BYTES ((size_t)WB_DWORDS * 4) // 22,544,384 — same requirement as verified round 2
#define NWG ((N_DIM / 128) * (M_DIM / 128))  // 86*32 = 2752
#define WG_PER_XCD (NWG / 8)                 // 344 (exact -> bijective remap)

// ---------------------------------------------------------------------------
// Repack: wp [K][N/2] (int32-widened uint8; low nibble = even n) ->
// WB layout: dword idx = ((n64*64 + kt)*64 + lane)*8 + ks*4 + t
//   nibble slot p = int4 at n = n64*64 + t*16 + (lane&15),
//   k = kt*64 + ks*32 + (lane>>4)*8 + j,  j = (p<4) ? 2p : 2(p-4)+1
// (verified in round 2)
// ---------------------------------------------------------------------------
__global__ __launch_bounds__(256) void repack_w_kernel(const int* __restrict__ wp,
                                                       u32* __restrict__ WB) {
  __shared__ unsigned char Wt[64][36];

  const u32 tid = threadIdx.x;
  const u32 n64 = blockIdx.x;
  const u32 kt  = blockIdx.y;

  {
    const u32 r = tid >> 2;
    const u32 c = (tid & 3u) * 8u;
    const int* src = wp + (size_t)(kt * 64u + r) * NHALF + n64 * 32u + c;
    int4 a = *(const int4*)(src);
    int4 b = *(const int4*)(src + 4);
    u32 lo = ((u32)a.x & 0xFFu) | (((u32)a.y & 0xFFu) << 8) |
             (((u32)a.z & 0xFFu) << 16) | (((u32)a.w & 0xFFu) << 24);
    u32 hi = ((u32)b.x & 0xFFu) | (((u32)b.y & 0xFFu) << 8) |
             (((u32)b.z & 0xFFu) << 16) | (((u32)b.w & 0xFFu) << 24);
    *(u32*)&Wt[r][c]      = lo;
    *(u32*)&Wt[r][c + 4u] = hi;
  }
  __syncthreads();

  const u32 tt    = tid & 3u;
  const u32 ks    = (tid >> 2) & 1u;
  const u32 lane0 = tid >> 3;
  const u32 l15   = lane0 & 15u;
  const u32 cb    = tt * 8u + (l15 >> 1);
  const u32 sh    = (l15 & 1u) * 4u;
  const size_t obase = ((size_t)(n64 * 64u + kt) * 64u) * 8u;

#pragma unroll
  for (int half = 0; half < 2; ++half) {
    const u32 lane = lane0 + (u32)half * 32u;
    const u32 kb   = ks * 32u + (lane >> 4) * 8u;
    u32 d = 0;
#pragma unroll
    for (int p = 0; p < 8; ++p) {
      const int j = (p < 4) ? (2 * p) : (2 * (p - 4) + 1);
      u32 byte = Wt[kb + (u32)j][cb];
      d |= ((byte >> sh) & 0xFu) << (4 * p);
    }
    WB[obase + tid + (u32)half * 256u] = d;
  }
}

// ---------------------------------------------------------------------------
// Main GEMM: 128x128 tile, BK=64, 4 waves 2Mx2N. Double-buffered As (32 KB),
// ONE barrier per K-tile, prefetch issued AFTER the barrier (overlaps MFMA).
// fp32 x staged via cvt_pkrtz (exact). XCD-aware n-major block remap.
// Workspace requirement identical to verified round 2 (WB only).
// ---------------------------------------------------------------------------
__global__ __launch_bounds__(256) void gemm_int4_f16(const float* __restrict__ x,
                                                     const u32* __restrict__ WB,
                                                     const float* __restrict__ wscale,
                                                     const float* __restrict__ wzero,
                                                     float* __restrict__ out) {
  __shared__ __align__(16) f16 As[2 * 128 * 64];  // 32 KB, slot-swizzled

  const u32 tid  = threadIdx.x;
  const u32 lane = tid & 63u;
  const u32 wave = tid >> 6;
  const u32 l15  = lane & 15u;
  const u32 quad = lane >> 4;
  const u32 wr   = wave >> 1;
  const u32 wc   = wave & 1u;

  // XCD remap: xcd = wgid%8 owns contiguous gid range; m varies fastest so
  // consecutive blocks on one XCD share the same WB n-slice (L2-resident).
  const u32 wgid = blockIdx.x;
  const u32 gid  = (wgid & 7u) * WG_PER_XCD + (wgid >> 3);
  const u32 n0   = (gid >> 5) * 128u;  // 32 m-tiles per n-tile
  const u32 m0   = (gid & 31u) * 128u;

  const u32 srow  = tid >> 3;
  const u32 sslot = tid & 7u;
  const float* xsrc = x + (size_t)(m0 + srow) * K_DIM + sslot * 8u;
  char* lds_dst = (char*)As + srow * 128u + ((sslot ^ (srow & 7u)) * 16u);

  const u32* wb_base = WB + ((size_t)((n0 >> 6) + wc) * KTN * 64u) * 8u + lane * 8u;

  const u32 abase = (wr * 64u + l15) * 64u;
  const u32 sw0   = ((quad)      ^ (l15 & 7u)) * 8u;
  const u32 sw1   = ((4u + quad) ^ (l15 & 7u)) * 8u;

  floatx4 acc[4][4];
  floatx4 zero4 = {0.f, 0.f, 0.f, 0.f};
#pragma unroll
  for (int i = 0; i < 4; ++i)
#pragma unroll
    for (int t = 0; t < 4; ++t) acc[i][t] = zero4;

  const u32 nidx0 = n0 + wc * 64u + l15;

  f16x8 nx[4];
  auto loadx = [&](u32 kt) {
    const float* p = xsrc + (size_t)kt * 64u;
#pragma unroll
    for (int it = 0; it < 4; ++it) {
      float4 f0 = *(const float4*)(p + (size_t)it * 32 * K_DIM);
      float4 f1 = *(const float4*)(p + (size_t)it * 32 * K_DIM + 4);
      union { f16x8 v; h2 h[4]; } u;
      u.h[0] = __builtin_bit_cast(h2, __builtin_amdgcn_cvt_pkrtz(f0.x, f0.y));
      u.h[1] = __builtin_bit_cast(h2, __builtin_amdgcn_cvt_pkrtz(f0.z, f0.w));
      u.h[2] = __builtin_bit_cast(h2, __builtin_amdgcn_cvt_pkrtz(f1.x, f1.y));
      u.h[3] = __builtin_bit_cast(h2, __builtin_amdgcn_cvt_pkrtz(f1.z, f1.w));
      nx[it] = u.v;
    }
  };

  // ---- prologue: tile 0 + group 0 scales ----
  loadx(0);
  uint4 nbq0 = *(const uint4*)(wb_base);
  uint4 nbq1 = *(const uint4*)(wb_base + 4u);
  float fs[4], fz[4];
#pragma unroll
  for (int t = 0; t < 4; ++t) {
    fs[t] = wscale[nidx0 + (u32)t * 16u];
    fz[t] = wzero [nidx0 + (u32)t * 16u];
  }
  h2 s2[4], z2[4];

  auto compute = [&](const f16* abuf, const uint4 bqa, const uint4 bqb) {
#pragma unroll
    for (int ks = 0; ks < 2; ++ks) {
      f16x8 af[4];
      const f16* ab = abuf + abase + (ks ? sw1 : sw0);
#pragma unroll
      for (int i = 0; i < 4; ++i)
        af[i] = *(const f16x8*)(ab + i * 16 * 64);
      const uint4 bqv = ks ? bqb : bqa;
      const u32 qs[4] = {bqv.x, bqv.y, bqv.z, bqv.w};
#pragma unroll
      for (int t = 0; t < 4; ++t) {
        const u32 q = qs[t];
        u32 w01 = (q & 0x000F000Fu) | 0x64006400u;
        u32 w23 = ((q >> 4) & 0x000F000Fu) | 0x64006400u;
        u32 w45 = ((q >> 8) & 0x000F000Fu) | 0x64006400u;
        u32 w67 = ((q >> 12) & 0x000F000Fu) | 0x64006400u;
        union { f16x8 v; h2 h[4]; } bf;
        bf.h[0] = (__builtin_bit_cast(h2, w01) - z2[t]) * s2[t];
        bf.h[1] = (__builtin_bit_cast(h2, w23) - z2[t]) * s2[t];
        bf.h[2] = (__builtin_bit_cast(h2, w45) - z2[t]) * s2[t];
        bf.h[3] = (__builtin_bit_cast(h2, w67) - z2[t]) * s2[t];
#pragma unroll
        for (int i = 0; i < 4; ++i)
          acc[i][t] = __builtin_amdgcn_mfma_f32_16x16x32_f16(af[i], bf.v, acc[i][t], 0, 0, 0);
      }
    }
  };

  for (u32 kt2 = 0; kt2 < KTN / 2; ++kt2) {
    // group scales for g = kt2 (fs/fz loaded >=1 K-tile ago)
#pragma unroll
    for (int t = 0; t < 4; ++t) {
      f16 sh_ = (f16)fs[t];
      f16 zh_ = (f16)(1024.0f + fz[t]);
      h2 sv = {sh_, sh_};
      h2 zv = {zh_, zh_};
      s2[t] = sv;
      z2[t] = zv;
    }
    // ======== body A: kt = 2*kt2, LDS buffer 0 ========
    {
      *(f16x8*)(lds_dst)         = nx[0];
      *(f16x8*)(lds_dst + 4096)  = nx[1];
      *(f16x8*)(lds_dst + 8192)  = nx[2];
      *(f16x8*)(lds_dst + 12288) = nx[3];
      uint4 cb0 = nbq0, cb1 = nbq1;
      __syncthreads();
      // prefetch kt+1 (always valid) — AFTER barrier, overlaps compute
      loadx(2u * kt2 + 1u);
      {
        const u32* wpn = wb_base + (size_t)(2u * kt2 + 1u) * 512u;
        nbq0 = *(const uint4*)(wpn);
        nbq1 = *(const uint4*)(wpn + 4u);
      }
      if (kt2 + 1u < (u32)(KTN / 2)) {  // scales for next group
        const u32 gofs = (kt2 + 1u) * (u32)N_DIM + nidx0;
#pragma unroll
        for (int t = 0; t < 4; ++t) {
          fs[t] = wscale[gofs + (u32)t * 16u];
          fz[t] = wzero [gofs + (u32)t * 16u];
        }
      }
      compute(As, cb0, cb1);
    }

    // ======== body B: kt = 2*kt2+1, LDS buffer 1 ========
    {
      *(f16x8*)(lds_dst + 16384)         = nx[0];
      *(f16x8*)(lds_dst + 16384 + 4096)  = nx[1];
      *(f16x8*)(lds_dst + 16384 + 8192)  = nx[2];
      *(f16x8*)(lds_dst + 16384 + 12288) = nx[3];
      uint4 cb0 = nbq0, cb1 = nbq1;
      __syncthreads();
      if (kt2 < (u32)(KTN / 2 - 1)) {  // prefetch kt+1 = 2*kt2+2
        loadx(2u * kt2 + 2u);
        const u32* wpn = wb_base + (size_t)(2u * kt2 + 2u) * 512u;
        nbq0 = *(const uint4*)(wpn);
        nbq1 = *(const uint4*)(wpn + 4u);
      }
      compute(As + 8192, cb0, cb1);
    }
  }

  const u32 col0 = n0 + wc * 64u + l15;
  const u32 row0 = m0 + wr * 64u + quad * 4u;
#pragma unroll
  for (int i = 0; i < 4; ++i)
#pragma unroll
    for (int t = 0; t < 4; ++t)
#pragma unroll
      for (int r = 0; r < 4; ++r)
        out[(size_t)(row0 + (u32)i * 16u + (u32)r) * N_DIM + col0 + (u32)t * 16u] =
            acc[i][t][r];
}

// ---------------------------------------------------------------------------
// Fallback GEMM (no workspace): legacy, not on the main path
// (ws_size >= WB_BYTES held in every passing round).
// ---------------------------------------------------------------------------
__global__ __launch_bounds__(256) void gemm_int4_direct(const float* __restrict__ x,
                                                        const int* __restrict__ wp,
                                                        const float* __restrict__ wscale,
                                                        const float* __restrict__ wzero,
                                                        float* __restrict__ out) {
  __shared__ __align__(16) bf16_t As[128 * 64];
  __shared__ unsigned char Wb[64 * 68];

  const u32 tid  = threadIdx.x;
  const u32 lane = tid & 63u;
  const u32 wave = tid >> 6;
  const u32 l15  = lane & 15u;
  const u32 quad = lane >> 4;

  const u32 n0 = blockIdx.x * 128u;
  const u32 m0 = blockIdx.y * 128u;

  const float* xsrc = x + (m0 + (tid >> 3)) * (u32)K_DIM + (tid & 7u) * 8u;
  char* lds_dst = (char*)(&As[0]) + tid * 16u;

  const u32 wrow = tid >> 2;
  const u32 wcol = (tid & 3u) * 16;
  const int* wsrc = wp + (size_t)wrow * NHALF + (n0 >> 1) + wcol;

  const u32 n_idx = n0 + wave * 32u + l15;
  const u32 bcol0 = (wave * 32u + l15) >> 1;
  const u32 bcol1 = (wave * 32u + 16u + l15) >> 1;
  const u32 nsh   = (l15 & 1u) * 4u;

  floatx4 acc[8][2];
  floatx4 zero4 = {0.f, 0.f, 0.f, 0.f};
#pragma unroll
  for (int i = 0; i < 8; ++i)
#pragma unroll
    for (int t = 0; t < 2; ++t) acc[i][t] = zero4;

  const bf16_t* afrag_base = &As[0] + l15 * 64u + quad * 8u;
  float sc[2], zs[2];

  for (u32 kt = 0; kt < K_DIM / 64u; ++kt) {
    const float* src = xsrc + kt * 64u;
    bf16x8 av[4];
#pragma unroll
    for (int it = 0; it < 4; ++it) {
      float4 f0 = *(const float4*)(src + it * 32 * K_DIM);
      float4 f1 = *(const float4*)(src + it * 32 * K_DIM + 4);
      bf16x8 v;
      v[0] = (bf16_t)f0.x; v[1] = (bf16_t)f0.y; v[2] = (bf16_t)f0.z; v[3] = (bf16_t)f0.w;
      v[4] = (bf16_t)f1.x; v[5] = (bf16_t)f1.y; v[6] = (bf16_t)f1.z; v[7] = (bf16_t)f1.w;
      av[it] = v;
    }

    const int* wsk = wsrc + (size_t)kt * 64u * NHALF;
    int4 wv[4];
#pragma unroll
    for (int q = 0; q < 4; ++q) wv[q] = *(const int4*)(wsk + q * 4);

    if ((kt & 1u) == 0u) {
      const u32 g = kt >> 1;
#pragma unroll
      for (int t = 0; t < 2; ++t) {
        float s = wscale[g * N_DIM + n_idx + t * 16u];
        float z = wzero[g * N_DIM + n_idx + t * 16u];
        sc[t] = s;
        zs[t] = s * z;
      }
    }

    __syncthreads();
#pragma unroll
    for (int it = 0; it < 4; ++it)
      *(bf16x8*)(lds_dst + it * 4096) = av[it];
#pragma unroll
    for (int q = 0; q < 4; ++q) {
      u32 d = ((u32)wv[q].x & 0xFFu) | (((u32)wv[q].y & 0xFFu) << 8) |
              (((u32)wv[q].z & 0xFFu) << 16) | (((u32)wv[q].w & 0xFFu) << 24);
      *(u32*)(&Wb[wrow * 68u + wcol + q * 4u]) = d;
    }
    __syncthreads();

#pragma unroll
    for (int ks = 0; ks < 2; ++ks) {
      bf16x8 af[8];
#pragma unroll
      for (int i = 0; i < 8; ++i)
        af[i] = *(const bf16x8*)(afrag_base + i * 16 * 64 + ks * 32);
#pragma unroll
      for (int t = 0; t < 2; ++t) {
        const u32 bc = t ? bcol1 : bcol0;
        bf16x8 bfr;
#pragma unroll
        for (int j = 0; j < 8; ++j) {
          u32 byte = Wb[(ks * 32u + quad * 8u + j) * 68u + bc];
          float w = (float)((byte >> nsh) & 0xFu) * sc[t] - zs[t];
          bfr[j] = (bf16_t)w;
        }
#pragma unroll
        for (int i = 0; i < 8; ++i)
          acc[i][t] = __builtin_amdgcn_mfma_f32_16x16x32_bf16(af[i], bfr, acc[i][t], 0, 0, 0);
      }
    }
  }

  const u32 col0 = n0 + wave * 32u + l15;
  const u32 row0 = m0 + quad * 4u;
#pragma unroll
  for (int i = 0; i < 8; ++i)
#pragma unroll
    for (int t = 0; t < 2; ++t)
#pragma unroll
      for (int r = 0; r < 4; ++r)
        out[(row0 + i * 16u + r) * (u32)N_DIM + col0 + t * 16u] = acc[i][t][r];
}

extern "C" void kernel_launch(void* const* d_in, const int* in_sizes, int n_in,
                              void* d_out, int out_size, void* d_ws, size_t ws_size,
                              hipStream_t stream) {
  const float* x      = (const float*)d_in[0];   // fp16 ref -> fp32 on device
  const int*   wp     = (const int*)d_in[1];     // uint8 -> int32 on device
  const float* wscale = (const float*)d_in[2];   // fp16 ref -> fp32
  const float* wzero  = (const float*)d_in[3];   // fp16 ref -> fp32
  float*       out    = (float*)d_out;           // fp16 ref output -> fp32

  if (ws_size >= WB_BYTES && d_ws != nullptr) {
    u32* WB = (u32*)d_ws;
    repack_w_kernel<<<dim3(N64T, KTN), 256, 0, stream>>>(wp, WB);
    gemm_int4_f16<<<NWG, 256, 0, stream>>>(x, WB, wscale, wzero, out);
  } else {
    gemm_int4_direct<<<dim3(N_DIM / 128, M_DIM / 128), 256, 0, stream>>>(x, wp, wscale, wzero, out);
  }
}

// Round 5
// 745.626 us; speedup vs baseline: 1.3759x; 1.3759x over previous
//
#include <hip/hip_runtime.h>
#include <hip/hip_bf16.h>
#include <stdint.h>

typedef __bf16 bf16_t;
typedef __bf16 bf16x8 __attribute__((ext_vector_type(8)));
typedef _Float16 f16;
typedef _Float16 f16x8 __attribute__((ext_vector_type(8)));
typedef _Float16 h2 __attribute__((ext_vector_type(2)));
typedef float floatx4 __attribute__((ext_vector_type(4)));
typedef uint32_t u32;

#define M_DIM 4096
#define K_DIM 4096
#define N_DIM 11008
#define GRP 128
#define NHALF (N_DIM / 2)        // 5504
#define N64T (N_DIM / 64)        // 172
#define KTN (K_DIM / 64)         // 64
#define WB_DWORDS (N64T * KTN * 64 * 8)  // 5,636,096 dwords
#define WB_BYTES ((size_t)WB_DWORDS * 4) // 22,544,384

// ---------------------------------------------------------------------------
// Repack: wp [K][N/2] (int32-widened uint8; low nibble = even n) ->
// WB layout: dword idx = ((n64*64 + kt)*64 + lane)*8 + ks*4 + t
//   nibble slot p = int4 at n = n64*64 + t*16 + (lane&15),
//   k = kt*64 + ks*32 + (lane>>4)*8 + j,  j = (p<4) ? 2p : 2(p-4)+1
// (verified rounds 2 & 4)
// ---------------------------------------------------------------------------
__global__ __launch_bounds__(256) void repack_w_kernel(const int* __restrict__ wp,
                                                       u32* __restrict__ WB) {
  __shared__ unsigned char Wt[64][36];

  const u32 tid = threadIdx.x;
  const u32 n64 = blockIdx.x;
  const u32 kt  = blockIdx.y;

  {
    const u32 r = tid >> 2;
    const u32 c = (tid & 3u) * 8u;
    const int* src = wp + (size_t)(kt * 64u + r) * NHALF + n64 * 32u + c;
    int4 a = *(const int4*)(src);
    int4 b = *(const int4*)(src + 4);
    u32 lo = ((u32)a.x & 0xFFu) | (((u32)a.y & 0xFFu) << 8) |
             (((u32)a.z & 0xFFu) << 16) | (((u32)a.w & 0xFFu) << 24);
    u32 hi = ((u32)b.x & 0xFFu) | (((u32)b.y & 0xFFu) << 8) |
             (((u32)b.z & 0xFFu) << 16) | (((u32)b.w & 0xFFu) << 24);
    *(u32*)&Wt[r][c]      = lo;
    *(u32*)&Wt[r][c + 4u] = hi;
  }
  __syncthreads();

  const u32 tt    = tid & 3u;
  const u32 ks    = (tid >> 2) & 1u;
  const u32 lane0 = tid >> 3;
  const u32 l15   = lane0 & 15u;
  const u32 cb    = tt * 8u + (l15 >> 1);
  const u32 sh    = (l15 & 1u) * 4u;
  const size_t obase = ((size_t)(n64 * 64u + kt) * 64u) * 8u;

#pragma unroll
  for (int half = 0; half < 2; ++half) {
    const u32 lane = lane0 + (u32)half * 32u;
    const u32 kb   = ks * 32u + (lane >> 4) * 8u;
    u32 d = 0;
#pragma unroll
    for (int p = 0; p < 8; ++p) {
      const int j = (p < 4) ? (2 * p) : (2 * (p - 4) + 1);
      u32 byte = Wt[kb + (u32)j][cb];
      d |= ((byte >> sh) & 0xFu) << (4 * p);
    }
    WB[obase + tid + (u32)half * 256u] = d;
  }
}

// ---------------------------------------------------------------------------
// Main GEMM: 128x128 tile, BK=64, 4 waves 2Mx2N. Single 16 KB As buffer,
// round-2 barrier structure and 2D grid (n fastest -> WB L2 reuse, x L3).
// ONE delta vs round 2: tile kt+1 global loads (x, B, scales) issued after
// barrier B, before compute(kt) — T14 overlap of HBM latency under MFMA.
// ---------------------------------------------------------------------------
__global__ __launch_bounds__(256) void gemm_int4_f16(const float* __restrict__ x,
                                                     const u32* __restrict__ WB,
                                                     const float* __restrict__ wscale,
                                                     const float* __restrict__ wzero,
                                                     float* __restrict__ out) {
  __shared__ __align__(16) f16 As[128 * 64];  // 16 KB, [m][k], slot-swizzled

  const u32 tid  = threadIdx.x;
  const u32 lane = tid & 63u;
  const u32 wave = tid >> 6;
  const u32 l15  = lane & 15u;
  const u32 quad = lane >> 4;
  const u32 wr   = wave >> 1;
  const u32 wc   = wave & 1u;

  const u32 n0 = blockIdx.x * 128u;
  const u32 m0 = blockIdx.y * 128u;

  const u32 srow  = tid >> 3;
  const u32 sslot = tid & 7u;
  const float* xsrc = x + (size_t)(m0 + srow) * K_DIM + sslot * 8u;
  char* lds_dst = (char*)As + srow * 128u + ((sslot ^ (srow & 7u)) * 16u);

  const u32* wb_base = WB + ((size_t)((n0 >> 6) + wc) * KTN * 64u) * 8u + lane * 8u;

  const u32 abase = (wr * 64u + l15) * 64u;
  const u32 sw0   = ((quad)      ^ (l15 & 7u)) * 8u;
  const u32 sw1   = ((4u + quad) ^ (l15 & 7u)) * 8u;

  floatx4 acc[4][4];
  floatx4 zero4 = {0.f, 0.f, 0.f, 0.f};
#pragma unroll
  for (int i = 0; i < 4; ++i)
#pragma unroll
    for (int t = 0; t < 4; ++t) acc[i][t] = zero4;

  const u32 nidx0 = n0 + wc * 64u + l15;

  f16x8 nx[4];
  auto loadx = [&](u32 kt) {
    const float* p = xsrc + (size_t)kt * 64u;
#pragma unroll
    for (int it = 0; it < 4; ++it) {
      float4 f0 = *(const float4*)(p + (size_t)it * 32 * K_DIM);
      float4 f1 = *(const float4*)(p + (size_t)it * 32 * K_DIM + 4);
      union { f16x8 v; h2 h[4]; } u;
      u.h[0] = __builtin_bit_cast(h2, __builtin_amdgcn_cvt_pkrtz(f0.x, f0.y));
      u.h[1] = __builtin_bit_cast(h2, __builtin_amdgcn_cvt_pkrtz(f0.z, f0.w));
      u.h[2] = __builtin_bit_cast(h2, __builtin_amdgcn_cvt_pkrtz(f1.x, f1.y));
      u.h[3] = __builtin_bit_cast(h2, __builtin_amdgcn_cvt_pkrtz(f1.z, f1.w));
      nx[it] = u.v;
    }
  };

  // ---- prologue: tile 0 + group 0 ----
  loadx(0);
  uint4 nbq0 = *(const uint4*)(wb_base);
  uint4 nbq1 = *(const uint4*)(wb_base + 4u);
  float fs[4], fz[4];
#pragma unroll
  for (int t = 0; t < 4; ++t) {
    fs[t] = wscale[nidx0 + (u32)t * 16u];
    fz[t] = wzero [nidx0 + (u32)t * 16u];
  }
  h2 s2[4], z2[4];

  auto compute = [&](const uint4 bqa, const uint4 bqb) {
#pragma unroll
    for (int ks = 0; ks < 2; ++ks) {
      f16x8 af[4];
      const f16* ab = As + abase + (ks ? sw1 : sw0);
#pragma unroll
      for (int i = 0; i < 4; ++i)
        af[i] = *(const f16x8*)(ab + i * 16 * 64);
      const uint4 bqv = ks ? bqb : bqa;
      const u32 qs[4] = {bqv.x, bqv.y, bqv.z, bqv.w};
#pragma unroll
      for (int t = 0; t < 4; ++t) {
        const u32 q = qs[t];
        u32 w01 = (q & 0x000F000Fu) | 0x64006400u;
        u32 w23 = ((q >> 4) & 0x000F000Fu) | 0x64006400u;
        u32 w45 = ((q >> 8) & 0x000F000Fu) | 0x64006400u;
        u32 w67 = ((q >> 12) & 0x000F000Fu) | 0x64006400u;
        union { f16x8 v; h2 h[4]; } bf;
        bf.h[0] = (__builtin_bit_cast(h2, w01) - z2[t]) * s2[t];  // Sterbenz-exact
        bf.h[1] = (__builtin_bit_cast(h2, w23) - z2[t]) * s2[t];
        bf.h[2] = (__builtin_bit_cast(h2, w45) - z2[t]) * s2[t];
        bf.h[3] = (__builtin_bit_cast(h2, w67) - z2[t]) * s2[t];
#pragma unroll
        for (int i = 0; i < 4; ++i)
          acc[i][t] = __builtin_amdgcn_mfma_f32_16x16x32_f16(af[i], bf.v, acc[i][t], 0, 0, 0);
      }
    }
  };

  for (u32 kt = 0; kt < KTN; ++kt) {
    if ((kt & 1u) == 0u) {  // group boundary: fs/fz loaded >=1 K-tile ago
#pragma unroll
      for (int t = 0; t < 4; ++t) {
        f16 sh_ = (f16)fs[t];
        f16 zh_ = (f16)(1024.0f + fz[t]);
        h2 sv = {sh_, sh_};
        h2 zv = {zh_, zh_};
        s2[t] = sv;
        z2[t] = zv;
      }
    }

    __syncthreads();  // A: all waves done reading As from iter kt-1
    *(f16x8*)(lds_dst)         = nx[0];
    *(f16x8*)(lds_dst + 4096)  = nx[1];
    *(f16x8*)(lds_dst + 8192)  = nx[2];
    *(f16x8*)(lds_dst + 12288) = nx[3];
    uint4 cb0 = nbq0, cb1 = nbq1;
    __syncthreads();  // B: tile kt visible

    if (kt + 1u < (u32)KTN) {  // prefetch kt+1 — overlaps compute(kt)
      loadx(kt + 1u);
      const u32* wpn = wb_base + (size_t)(kt + 1u) * 512u;
      nbq0 = *(const uint4*)(wpn);
      nbq1 = *(const uint4*)(wpn + 4u);
      if (((kt + 1u) & 1u) == 0u) {  // scales for next group
        const u32 gofs = ((kt + 1u) >> 1) * (u32)N_DIM + nidx0;
#pragma unroll
        for (int t = 0; t < 4; ++t) {
          fs[t] = wscale[gofs + (u32)t * 16u];
          fz[t] = wzero [gofs + (u32)t * 16u];
        }
      }
    }

    compute(cb0, cb1);
  }

  // C/D layout: col = lane&15 (n), row = quad*4 + r (m)
  const u32 col0 = n0 + wc * 64u + l15;
  const u32 row0 = m0 + wr * 64u + quad * 4u;
#pragma unroll
  for (int i = 0; i < 4; ++i)
#pragma unroll
    for (int t = 0; t < 4; ++t)
#pragma unroll
      for (int r = 0; r < 4; ++r)
        out[(size_t)(row0 + (u32)i * 16u + (u32)r) * N_DIM + col0 + (u32)t * 16u] =
            acc[i][t][r];
}

// ---------------------------------------------------------------------------
// Fallback GEMM (no workspace): legacy, not on the main path.
// ---------------------------------------------------------------------------
__global__ __launch_bounds__(256) void gemm_int4_direct(const float* __restrict__ x,
                                                        const int* __restrict__ wp,
                                                        const float* __restrict__ wscale,
                                                        const float* __restrict__ wzero,
                                                        float* __restrict__ out) {
  __shared__ __align__(16) bf16_t As[128 * 64];
  __shared__ unsigned char Wb[64 * 68];

  const u32 tid  = threadIdx.x;
  const u32 lane = tid & 63u;
  const u32 wave = tid >> 6;
  const u32 l15  = lane & 15u;
  const u32 quad = lane >> 4;

  const u32 n0 = blockIdx.x * 128u;
  const u32 m0 = blockIdx.y * 128u;

  const float* xsrc = x + (m0 + (tid >> 3)) * (u32)K_DIM + (tid & 7u) * 8u;
  char* lds_dst = (char*)(&As[0]) + tid * 16u;

  const u32 wrow = tid >> 2;
  const u32 wcol = (tid & 3u) * 16;
  const int* wsrc = wp + (size_t)wrow * NHALF + (n0 >> 1) + wcol;

  const u32 n_idx = n0 + wave * 32u + l15;
  const u32 bcol0 = (wave * 32u + l15) >> 1;
  const u32 bcol1 = (wave * 32u + 16u + l15) >> 1;
  const u32 nsh   = (l15 & 1u) * 4u;

  floatx4 acc[8][2];
  floatx4 zero4 = {0.f, 0.f, 0.f, 0.f};
#pragma unroll
  for (int i = 0; i < 8; ++i)
#pragma unroll
    for (int t = 0; t < 2; ++t) acc[i][t] = zero4;

  const bf16_t* afrag_base = &As[0] + l15 * 64u + quad * 8u;
  float sc[2], zs[2];

  for (u32 kt = 0; kt < K_DIM / 64u; ++kt) {
    const float* src = xsrc + kt * 64u;
    bf16x8 av[4];
#pragma unroll
    for (int it = 0; it < 4; ++it) {
      float4 f0 = *(const float4*)(src + it * 32 * K_DIM);
      float4 f1 = *(const float4*)(src + it * 32 * K_DIM + 4);
      bf16x8 v;
      v[0] = (bf16_t)f0.x; v[1] = (bf16_t)f0.y; v[2] = (bf16_t)f0.z; v[3] = (bf16_t)f0.w;
      v[4] = (bf16_t)f1.x; v[5] = (bf16_t)f1.y; v[6] = (bf16_t)f1.z; v[7] = (bf16_t)f1.w;
      av[it] = v;
    }

    const int* wsk = wsrc + (size_t)kt * 64u * NHALF;
    int4 wv[4];
#pragma unroll
    for (int q = 0; q < 4; ++q) wv[q] = *(const int4*)(wsk + q * 4);

    if ((kt & 1u) == 0u) {
      const u32 g = kt >> 1;
#pragma unroll
      for (int t = 0; t < 2; ++t) {
        float s = wscale[g * N_DIM + n_idx + t * 16u];
        float z = wzero[g * N_DIM + n_idx + t * 16u];
        sc[t] = s;
        zs[t] = s * z;
      }
    }

    __syncthreads();
#pragma unroll
    for (int it = 0; it < 4; ++it)
      *(bf16x8*)(lds_dst + it * 4096) = av[it];
#pragma unroll
    for (int q = 0; q < 4; ++q) {
      u32 d = ((u32)wv[q].x & 0xFFu) | (((u32)wv[q].y & 0xFFu) << 8) |
              (((u32)wv[q].z & 0xFFu) << 16) | (((u32)wv[q].w & 0xFFu) << 24);
      *(u32*)(&Wb[wrow * 68u + wcol + q * 4u]) = d;
    }
    __syncthreads();

#pragma unroll
    for (int ks = 0; ks < 2; ++ks) {
      bf16x8 af[8];
#pragma unroll
      for (int i = 0; i < 8; ++i)
        af[i] = *(const bf16x8*)(afrag_base + i * 16 * 64 + ks * 32);
#pragma unroll
      for (int t = 0; t < 2; ++t) {
        const u32 bc = t ? bcol1 : bcol0;
        bf16x8 bfr;
#pragma unroll
        for (int j = 0; j < 8; ++j) {
          u32 byte = Wb[(ks * 32u + quad * 8u + j) * 68u + bc];
          float w = (float)((byte >> nsh) & 0xFu) * sc[t] - zs[t];
          bfr[j] = (bf16_t)w;
        }
#pragma unroll
        for (int i = 0; i < 8; ++i)
          acc[i][t] = __builtin_amdgcn_mfma_f32_16x16x32_bf16(af[i], bfr, acc[i][t], 0, 0, 0);
      }
    }
  }

  const u32 col0 = n0 + wave * 32u + l15;
  const u32 row0 = m0 + quad * 4u;
#pragma unroll
  for (int i = 0; i < 8; ++i)
#pragma unroll
    for (int t = 0; t < 2; ++t)
#pragma unroll
      for (int r = 0; r < 4; ++r)
        out[(row0 + i * 16u + r) * (u32)N_DIM + col0 + t * 16u] = acc[i][t][r];
}

extern "C" void kernel_launch(void* const* d_in, const int* in_sizes, int n_in,
                              void* d_out, int out_size, void* d_ws, size_t ws_size,
                              hipStream_t stream) {
  const float* x      = (const float*)d_in[0];   // fp16 ref -> fp32 on device
  const int*   wp     = (const int*)d_in[1];     // uint8 -> int32 on device
  const float* wscale = (const float*)d_in[2];   // fp16 ref -> fp32
  const float* wzero  = (const float*)d_in[3];   // fp16 ref -> fp32
  float*       out    = (float*)d_out;           // fp16 ref output -> fp32

  if (ws_size >= WB_BYTES && d_ws != nullptr) {
    u32* WB = (u32*)d_ws;
    repack_w_kernel<<<dim3(N64T, KTN), 256, 0, stream>>>(wp, WB);
    gemm_int4_f16<<<dim3(N_DIM / 128, M_DIM / 128), 256, 0, stream>>>(x, WB, wscale, wzero, out);
  } else {
    gemm_int4_direct<<<dim3(N_DIM / 128, M_DIM / 128), 256, 0, stream>>>(x, wp, wscale, wzero, out);
  }
}

// Round 6
// 666.677 us; speedup vs baseline: 1.5388x; 1.1184x over previous
//
#include <hip/hip_runtime.h>
#include <hip/hip_bf16.h>
#include <stdint.h>

typedef __bf16 bf16_t;
typedef __bf16 bf16x8 __attribute__((ext_vector_type(8)));
typedef _Float16 f16;
typedef _Float16 f16x8 __attribute__((ext_vector_type(8)));
typedef _Float16 h2 __attribute__((ext_vector_type(2)));
typedef float floatx4 __attribute__((ext_vector_type(4)));
typedef uint32_t u32;

#define M_DIM 4096
#define K_DIM 4096
#define N_DIM 11008
#define GRP 128
#define NHALF (N_DIM / 2)        // 5504
#define N64T (N_DIM / 64)        // 172
#define KTN (K_DIM / 64)         // 64
#define WB_DWORDS (N64T * KTN * 64 * 8)  // 5,636,096 dwords
#define WB_BYTES ((size_t)WB_DWORDS * 4) // 22,544,384

// ---------------------------------------------------------------------------
// Repack: wp [K][N/2] (int32-widened uint8; low nibble = even n) ->
// WB layout: dword idx = ((n64*64 + kt)*64 + lane)*8 + ks*4 + t
//   nibble slot p = int4 at n = n64*64 + t*16 + (lane&15),
//   k = kt*64 + ks*32 + (lane>>4)*8 + j,  j = (p<4) ? 2p : 2(p-4)+1
// (verified rounds 2, 4, 5)
// ---------------------------------------------------------------------------
__global__ __launch_bounds__(256) void repack_w_kernel(const int* __restrict__ wp,
                                                       u32* __restrict__ WB) {
  __shared__ unsigned char Wt[64][36];

  const u32 tid = threadIdx.x;
  const u32 n64 = blockIdx.x;
  const u32 kt  = blockIdx.y;

  {
    const u32 r = tid >> 2;
    const u32 c = (tid & 3u) * 8u;
    const int* src = wp + (size_t)(kt * 64u + r) * NHALF + n64 * 32u + c;
    int4 a = *(const int4*)(src);
    int4 b = *(const int4*)(src + 4);
    u32 lo = ((u32)a.x & 0xFFu) | (((u32)a.y & 0xFFu) << 8) |
             (((u32)a.z & 0xFFu) << 16) | (((u32)a.w & 0xFFu) << 24);
    u32 hi = ((u32)b.x & 0xFFu) | (((u32)b.y & 0xFFu) << 8) |
             (((u32)b.z & 0xFFu) << 16) | (((u32)b.w & 0xFFu) << 24);
    *(u32*)&Wt[r][c]      = lo;
    *(u32*)&Wt[r][c + 4u] = hi;
  }
  __syncthreads();

  const u32 tt    = tid & 3u;
  const u32 ks    = (tid >> 2) & 1u;
  const u32 lane0 = tid >> 3;
  const u32 l15   = lane0 & 15u;
  const u32 cb    = tt * 8u + (l15 >> 1);
  const u32 sh    = (l15 & 1u) * 4u;
  const size_t obase = ((size_t)(n64 * 64u + kt) * 64u) * 8u;

#pragma unroll
  for (int half = 0; half < 2; ++half) {
    const u32 lane = lane0 + (u32)half * 32u;
    const u32 kb   = ks * 32u + (lane >> 4) * 8u;
    u32 d = 0;
#pragma unroll
    for (int p = 0; p < 8; ++p) {
      const int j = (p < 4) ? (2 * p) : (2 * (p - 4) + 1);
      u32 byte = Wt[kb + (u32)j][cb];
      d |= ((byte >> sh) & 0xFu) << (4 * p);
    }
    WB[obase + tid + (u32)half * 256u] = d;
  }
}

// ---------------------------------------------------------------------------
// Main GEMM: 128x128 tile, BK=64, 4 waves in 1M x 4N (128m x 32n per wave).
// Single delta vs verified round-2 kernel (2Mx2N, 504us): the 1x4 split
// halves per-lane B-dequant (8->4 dwords, 120->60 VALU) at the cost of
// doubled A ds_reads (8->16/lane) on the underutilized LDS pipe.
// Same barriers, same staging, same WB layout, no prefetch (VGPR <= 64).
// ---------------------------------------------------------------------------
__global__ __launch_bounds__(256) void gemm_int4_f16(const float* __restrict__ x,
                                                     const u32* __restrict__ WB,
                                                     const float* __restrict__ wscale,
                                                     const float* __restrict__ wzero,
                                                     float* __restrict__ out) {
  __shared__ __align__(16) f16 As[128 * 64];  // 16 KB, [m][k], slot-swizzled

  const u32 tid  = threadIdx.x;
  const u32 lane = tid & 63u;
  const u32 wave = tid >> 6;
  const u32 l15  = lane & 15u;
  const u32 quad = lane >> 4;

  const u32 n0 = blockIdx.x * 128u;
  const u32 m0 = blockIdx.y * 128u;

  // staging: thread stages rows (tid>>3)+32*it, f32 cols (tid&7)*8..+7
  const u32 srow  = tid >> 3;
  const u32 sslot = tid & 7u;
  const float* xsrc = x + (size_t)(m0 + srow) * K_DIM + sslot * 8u;
  char* lds_dst = (char*)As + srow * 128u + ((sslot ^ (srow & 7u)) * 16u);

  // B: wave w owns n-range [n0 + w*32, +32) = n64-tile (w>>1), t in {tb, tb+1}
  // per K-tile per lane: 2 dwords per ks, 8B-aligned (tb even) -> uint2 loads
  const u32* wb_lane = WB + ((size_t)((n0 >> 6) + (wave >> 1)) * KTN * 512u)
                         + lane * 8u + (wave & 1u) * 2u;

  // A-fragment read offsets (swizzled slot = (ks*4+quad) ^ (row&7); i*16 ≡ 0 mod 8)
  const u32 sw0 = ((quad)      ^ (l15 & 7u)) * 8u;
  const u32 sw1 = ((4u + quad) ^ (l15 & 7u)) * 8u;
  const f16* a0 = As + l15 * 64u + sw0;
  const f16* a1 = As + l15 * 64u + sw1;

  floatx4 acc[8][2];
  floatx4 zero4 = {0.f, 0.f, 0.f, 0.f};
#pragma unroll
  for (int i = 0; i < 8; ++i)
#pragma unroll
    for (int t = 0; t < 2; ++t) acc[i][t] = zero4;

  const u32 nidx0 = n0 + wave * 32u + l15;
  h2 s2[2], z2[2];

  for (u32 kt = 0; kt < KTN; ++kt) {
    // ---- global loads for this tile ----
    const float* src = xsrc + kt * 64u;
    f16x8 nx[4];
#pragma unroll
    for (int it = 0; it < 4; ++it) {
      float4 f0 = *(const float4*)(src + (size_t)it * 32 * K_DIM);
      float4 f1 = *(const float4*)(src + (size_t)it * 32 * K_DIM + 4);
      union { f16x8 v; h2 h[4]; } u;
      u.h[0] = __builtin_bit_cast(h2, __builtin_amdgcn_cvt_pkrtz(f0.x, f0.y));  // exact
      u.h[1] = __builtin_bit_cast(h2, __builtin_amdgcn_cvt_pkrtz(f0.z, f0.w));
      u.h[2] = __builtin_bit_cast(h2, __builtin_amdgcn_cvt_pkrtz(f1.x, f1.y));
      u.h[3] = __builtin_bit_cast(h2, __builtin_amdgcn_cvt_pkrtz(f1.z, f1.w));
      nx[it] = u.v;
    }

    const u32* wp8 = wb_lane + (size_t)kt * 512u;
    uint2 bqa = *(const uint2*)(wp8);       // ks=0: t = tb, tb+1
    uint2 bqb = *(const uint2*)(wp8 + 4u);  // ks=1

    if ((kt & 1u) == 0u) {  // group boundary (GRP=128 = 2 K-tiles)
      const u32 g = kt >> 1;
#pragma unroll
      for (int t = 0; t < 2; ++t) {
        float s = wscale[g * N_DIM + nidx0 + (u32)t * 16u];
        float z = wzero [g * N_DIM + nidx0 + (u32)t * 16u];
        f16 sh_ = (f16)s;               // exact (source was fp16)
        f16 zh_ = (f16)(1024.0f + z);   // exact (z integer in [0,16))
        h2 sv = {sh_, sh_};
        h2 zv = {zh_, zh_};
        s2[t] = sv;
        z2[t] = zv;
      }
    }

    __syncthreads();  // A: all waves done reading As from iter kt-1
    *(f16x8*)(lds_dst)         = nx[0];
    *(f16x8*)(lds_dst + 4096)  = nx[1];
    *(f16x8*)(lds_dst + 8192)  = nx[2];
    *(f16x8*)(lds_dst + 12288) = nx[3];
    __syncthreads();  // B: tile kt visible

#pragma unroll
    for (int ks = 0; ks < 2; ++ks) {
      const u32 qw0 = ks ? bqb.x : bqa.x;
      const u32 qw1 = ks ? bqb.y : bqa.y;
      f16x8 bf[2];
#pragma unroll
      for (int t = 0; t < 2; ++t) {
        const u32 q = t ? qw1 : qw0;
        u32 w01 = (q & 0x000F000Fu) | 0x64006400u;
        u32 w23 = ((q >> 4) & 0x000F000Fu) | 0x64006400u;
        u32 w45 = ((q >> 8) & 0x000F000Fu) | 0x64006400u;
        u32 w67 = ((q >> 12) & 0x000F000Fu) | 0x64006400u;
        union { f16x8 v; h2 h[4]; } b;
        b.h[0] = (__builtin_bit_cast(h2, w01) - z2[t]) * s2[t];  // Sterbenz-exact
        b.h[1] = (__builtin_bit_cast(h2, w23) - z2[t]) * s2[t];
        b.h[2] = (__builtin_bit_cast(h2, w45) - z2[t]) * s2[t];
        b.h[3] = (__builtin_bit_cast(h2, w67) - z2[t]) * s2[t];
        bf[t] = b.v;
      }
      const f16* ab = ks ? a1 : a0;
#pragma unroll
      for (int i = 0; i < 8; ++i) {
        f16x8 af = *(const f16x8*)(ab + i * 16 * 64);
        acc[i][0] = __builtin_amdgcn_mfma_f32_16x16x32_f16(af, bf[0], acc[i][0], 0, 0, 0);
        acc[i][1] = __builtin_amdgcn_mfma_f32_16x16x32_f16(af, bf[1], acc[i][1], 0, 0, 0);
      }
    }
  }

  // C/D layout: col = lane&15 (n), row = quad*4 + r (m)
  const u32 col0 = n0 + wave * 32u + l15;
  const u32 row0 = m0 + quad * 4u;
#pragma unroll
  for (int i = 0; i < 8; ++i)
#pragma unroll
    for (int t = 0; t < 2; ++t)
#pragma unroll
      for (int r = 0; r < 4; ++r)
        out[(size_t)(row0 + (u32)i * 16u + (u32)r) * N_DIM + col0 + (u32)t * 16u] =
            acc[i][t][r];
}

// ---------------------------------------------------------------------------
// Fallback GEMM (no workspace): legacy, not on the main path.
// ---------------------------------------------------------------------------
__global__ __launch_bounds__(256) void gemm_int4_direct(const float* __restrict__ x,
                                                        const int* __restrict__ wp,
                                                        const float* __restrict__ wscale,
                                                        const float* __restrict__ wzero,
                                                        float* __restrict__ out) {
  __shared__ __align__(16) bf16_t As[128 * 64];
  __shared__ unsigned char Wb[64 * 68];

  const u32 tid  = threadIdx.x;
  const u32 lane = tid & 63u;
  const u32 wave = tid >> 6;
  const u32 l15  = lane & 15u;
  const u32 quad = lane >> 4;

  const u32 n0 = blockIdx.x * 128u;
  const u32 m0 = blockIdx.y * 128u;

  const float* xsrc = x + (m0 + (tid >> 3)) * (u32)K_DIM + (tid & 7u) * 8u;
  char* lds_dst = (char*)(&As[0]) + tid * 16u;

  const u32 wrow = tid >> 2;
  const u32 wcol = (tid & 3u) * 16;
  const int* wsrc = wp + (size_t)wrow * NHALF + (n0 >> 1) + wcol;

  const u32 n_idx = n0 + wave * 32u + l15;
  const u32 bcol0 = (wave * 32u + l15) >> 1;
  const u32 bcol1 = (wave * 32u + 16u + l15) >> 1;
  const u32 nsh   = (l15 & 1u) * 4u;

  floatx4 acc[8][2];
  floatx4 zero4 = {0.f, 0.f, 0.f, 0.f};
#pragma unroll
  for (int i = 0; i < 8; ++i)
#pragma unroll
    for (int t = 0; t < 2; ++t) acc[i][t] = zero4;

  const bf16_t* afrag_base = &As[0] + l15 * 64u + quad * 8u;
  float sc[2], zs[2];

  for (u32 kt = 0; kt < K_DIM / 64u; ++kt) {
    const float* src = xsrc + kt * 64u;
    bf16x8 av[4];
#pragma unroll
    for (int it = 0; it < 4; ++it) {
      float4 f0 = *(const float4*)(src + it * 32 * K_DIM);
      float4 f1 = *(const float4*)(src + it * 32 * K_DIM + 4);
      bf16x8 v;
      v[0] = (bf16_t)f0.x; v[1] = (bf16_t)f0.y; v[2] = (bf16_t)f0.z; v[3] = (bf16_t)f0.w;
      v[4] = (bf16_t)f1.x; v[5] = (bf16_t)f1.y; v[6] = (bf16_t)f1.z; v[7] = (bf16_t)f1.w;
      av[it] = v;
    }

    const int* wsk = wsrc + (size_t)kt * 64u * NHALF;
    int4 wv[4];
#pragma unroll
    for (int q = 0; q < 4; ++q) wv[q] = *(const int4*)(wsk + q * 4);

    if ((kt & 1u) == 0u) {
      const u32 g = kt >> 1;
#pragma unroll
      for (int t = 0; t < 2; ++t) {
        float s = wscale[g * N_DIM + n_idx + t * 16u];
        float z = wzero[g * N_DIM + n_idx + t * 16u];
        sc[t] = s;
        zs[t] = s * z;
      }
    }

    __syncthreads();
#pragma unroll
    for (int it = 0; it < 4; ++it)
      *(bf16x8*)(lds_dst + it * 4096) = av[it];
#pragma unroll
    for (int q = 0; q < 4; ++q) {
      u32 d = ((u32)wv[q].x & 0xFFu) | (((u32)wv[q].y & 0xFFu) << 8) |
              (((u32)wv[q].z & 0xFFu) << 16) | (((u32)wv[q].w & 0xFFu) << 24);
      *(u32*)(&Wb[wrow * 68u + wcol + q * 4u]) = d;
    }
    __syncthreads();

#pragma unroll
    for (int ks = 0; ks < 2; ++ks) {
      bf16x8 af[8];
#pragma unroll
      for (int i = 0; i < 8; ++i)
        af[i] = *(const bf16x8*)(afrag_base + i * 16 * 64 + ks * 32);
#pragma unroll
      for (int t = 0; t < 2; ++t) {
        const u32 bc = t ? bcol1 : bcol0;
        bf16x8 bfr;
#pragma unroll
        for (int j = 0; j < 8; ++j) {
          u32 byte = Wb[(ks * 32u + quad * 8u + j) * 68u + bc];
          float w = (float)((byte >> nsh) & 0xFu) * sc[t] - zs[t];
          bfr[j] = (bf16_t)w;
        }
#pragma unroll
        for (int i = 0; i < 8; ++i)
          acc[i][t] = __builtin_amdgcn_mfma_f32_16x16x32_bf16(af[i], bfr, acc[i][t], 0, 0, 0);
      }
    }
  }

  const u32 col0 = n0 + wave * 32u + l15;
  const u32 row0 = m0 + quad * 4u;
#pragma unroll
  for (int i = 0; i < 8; ++i)
#pragma unroll
    for (int t = 0; t < 2; ++t)
#pragma unroll
      for (int r = 0; r < 4; ++r)
        out[(row0 + i * 16u + r) * (u32)N_DIM + col0 + t * 16u] = acc[i][t][r];
}

extern "C" void kernel_launch(void* const* d_in, const int* in_sizes, int n_in,
                              void* d_out, int out_size, void* d_ws, size_t ws_size,
                              hipStream_t stream) {
  const float* x      = (const float*)d_in[0];   // fp16 ref -> fp32 on device
  const int*   wp     = (const int*)d_in[1];     // uint8 -> int32 on device
  const float* wscale = (const float*)d_in[2];   // fp16 ref -> fp32
  const float* wzero  = (const float*)d_in[3];   // fp16 ref -> fp32
  float*       out    = (float*)d_out;           // fp16 ref output -> fp32

  if (ws_size >= WB_BYTES && d_ws != nullptr) {
    u32* WB = (u32*)d_ws;
    repack_w_kernel<<<dim3(N64T, KTN), 256, 0, stream>>>(wp, WB);
    gemm_int4_f16<<<dim3(N_DIM / 128, M_DIM / 128), 256, 0, stream>>>(x, WB, wscale, wzero, out);
  } else {
    gemm_int4_direct<<<dim3(N_DIM / 128, M_DIM / 128), 256, 0, stream>>>(x, wp, wscale, wzero, out);
  }
}